// Round 4
// baseline (352.906 us; speedup 1.0000x reference)
//
#include <hip/hip_runtime.h>
#include <stdint.h>

typedef unsigned long long u64;
typedef unsigned int u32;

#define B_    32
#define CIN   256
#define COUT  256
#define H_    56
#define W_    56
#define HW    3136            // H_*W_
#define NPOS  100352          // B_*HW
#define NROW  1792            // B_*H_
#define NPACKBLK 392          // (NPOS/4/256) * 4 j-chunks

// ---- workspace layout (bytes) ----
// 0       : wbits u64[256*36]        73728
// 73728   : alpha f32[256]           1024
// 74752   : ssum  i32[256]           1024
// 75776   : qsum  u64[256]           2048
// 79872   : xbits u64[NPOS*4]        3211264   (ends 3291136)
// 3291136 : S     s16[NPOS*256] NHWC 51380224

// ---------------- Kernel 1: prep (x bitpack ∪ weight prep), grid-partitioned ----------------
__global__ __launch_bounds__(256) void k_prep(
    const float* __restrict__ x,     // [B, C, H, W]
    const float* __restrict__ wgt,   // [O=256, I=256, 3, 3]
    u64* __restrict__ xbits,         // [NPOS][4]
    u64* __restrict__ wbits,         // [O][9 taps][4 words]
    float* __restrict__ alpha,
    int* __restrict__ ssum,
    unsigned long long* __restrict__ qsum)
{
    const int tid = threadIdx.x;

    if (blockIdx.x < NPACKBLK) {
        // ---- pack sign(x): 4 positions per thread via float4 ----
        const int j = blockIdx.x / 98;                   // channel chunk
        const int p4 = (blockIdx.x - j * 98) * 256 + tid;
        const int pos0 = p4 * 4;                          // 4-aligned; HW%4==0 so no b crossing
        const int b = pos0 / HW;
        const int hw = pos0 - b * HW;
        const float* xp = x + (size_t)b * CIN * HW + (size_t)j * 64 * HW + hw;
        u64 bits[4] = {0, 0, 0, 0};
        for (int k = 0; k < 64; ++k) {
            const float4 v = *(const float4*)(xp + (size_t)k * HW);
            bits[0] |= (u64)(v.x > 0.0f) << k;
            bits[1] |= (u64)(v.y > 0.0f) << k;
            bits[2] |= (u64)(v.z > 0.0f) << k;
            bits[3] |= (u64)(v.w > 0.0f) << k;
        }
#pragma unroll
        for (int m = 0; m < 4; ++m)
            xbits[(size_t)(pos0 + m) * 4 + j] = bits[m];
        return;
    }

    // ---- weight prep: mean-center, clip, alpha, bitpack; zero stats ----
    const int o = blockIdx.x - NPACKBLK;
    const int i = tid;                 // input channel
    const int wave = i >> 6, lane = i & 63;
    __shared__ float sred[4][12];

    if (i == 0) { ssum[o] = 0; qsum[o] = 0ULL; }

    float w9[9];
#pragma unroll
    for (int t = 0; t < 9; ++t) w9[t] = wgt[(o * 256 + i) * 9 + t];

    float m[9];
#pragma unroll
    for (int t = 0; t < 9; ++t) m[t] = w9[t];
#pragma unroll
    for (int s = 1; s < 64; s <<= 1)
#pragma unroll
        for (int t = 0; t < 9; ++t) m[t] += __shfl_xor(m[t], s, 64);
    if (lane == 0) {
#pragma unroll
        for (int t = 0; t < 9; ++t) sred[wave][t] = m[t];
    }
    __syncthreads();
#pragma unroll
    for (int t = 0; t < 9; ++t)
        m[t] = (sred[0][t] + sred[1][t] + sred[2][t] + sred[3][t]) * (1.0f / 256.0f);

    float wc[9];
    float asum = 0.0f;
#pragma unroll
    for (int t = 0; t < 9; ++t) {
        float v = w9[t] - m[t];
        v = fminf(fmaxf(v, -1.0f), 1.0f);
        wc[t] = v;
        asum += fabsf(v);
    }
#pragma unroll
    for (int s = 1; s < 64; s <<= 1) asum += __shfl_xor(asum, s, 64);
    __syncthreads();
    if (lane == 0) sred[wave][9] = asum;
    __syncthreads();
    if (i == 0)
        alpha[o] = (sred[0][9] + sred[1][9] + sred[2][9] + sred[3][9]) * (1.0f / 2304.0f);

#pragma unroll
    for (int t = 0; t < 9; ++t) {
        u64 bb = __ballot(wc[t] > 0.0f);   // bit=1 <-> +1
        if (lane == 0) wbits[o * 36 + t * 4 + wave] = bb;
    }
}

// ---------------- conv row processor: lane-pair split over channel words ----------------
// t2 = tile + 2*half; index (kh*56+col)*4 + jj, jj in {0,1}. wr[tap*2+jj].
// After the shfl both lanes of a pair hold the full sum, so stats accumulate
// unpredicated; only the store is predicated on half==0.
template<int R0, int R1>
__device__ __forceinline__ void run_row2(
    const u64* __restrict__ t2,
    const u64 wr[18],
    short* __restrict__ srow,
    const bool st,
    int& s_acc, int& q_acc)
{
    constexpr int NR = R1 - R0 + 1;

    // ---- w = 0 : kw in {1,2} -> cols 0,1 ----
    {
        int acc = 0;
#pragma unroll
        for (int kh = R0; kh <= R1; ++kh)
#pragma unroll
            for (int kw = 1; kw <= 2; ++kw)
#pragma unroll
                for (int jj = 0; jj < 2; ++jj)
                    acc += (int)__popcll(t2[(kh * 56 + (kw - 1)) * 4 + jj] ^ wr[(kh * 3 + kw) * 2 + jj]);
        acc += __shfl_xor(acc, 1, 64);
        int S = NR * 2 * 256 - 2 * acc;
        if (st) srow[0] = (short)S;
        s_acc += S; q_acc += S * S;
    }

    // ring: slot(col) = col % 3; preload cols 0,1
    u64 xc[3][3][2];
#pragma unroll
    for (int kh = R0; kh <= R1; ++kh)
#pragma unroll
        for (int jj = 0; jj < 2; ++jj) {
            xc[0][kh][jj] = t2[(kh * 56 + 0) * 4 + jj];
            xc[1][kh][jj] = t2[(kh * 56 + 1) * 4 + jj];
        }

    for (int wb = 1; wb <= 52; wb += 3) {
#pragma unroll
        for (int u = 0; u < 3; ++u) {
            const int w = wb + u;                 // 1..54, w % 3 == (1+u) % 3
#pragma unroll
            for (int kh = R0; kh <= R1; ++kh)
#pragma unroll
                for (int jj = 0; jj < 2; ++jj)
                    xc[(u + 2) % 3][kh][jj] = t2[(kh * 56 + (w + 1)) * 4 + jj];
            int acc = 0;
#pragma unroll
            for (int kh = R0; kh <= R1; ++kh)
#pragma unroll
                for (int kw = 0; kw < 3; ++kw)
#pragma unroll
                    for (int jj = 0; jj < 2; ++jj)
                        acc += (int)__popcll(xc[(u + kw) % 3][kh][jj] ^ wr[(kh * 3 + kw) * 2 + jj]);
            acc += __shfl_xor(acc, 1, 64);
            int S = NR * 3 * 256 - 2 * acc;
            if (st) srow[(size_t)w * 256] = (short)S;
            s_acc += S; q_acc += S * S;
        }
    }

    // ---- w = 55 : kw in {0,1}; cols 54,55 live in slots 0,1 ----
    {
        int acc = 0;
#pragma unroll
        for (int kh = R0; kh <= R1; ++kh)
#pragma unroll
            for (int kw = 0; kw <= 1; ++kw)
#pragma unroll
                for (int jj = 0; jj < 2; ++jj)
                    acc += (int)__popcll(xc[(54 + kw) % 3][kh][jj] ^ wr[(kh * 3 + kw) * 2 + jj]);
        acc += __shfl_xor(acc, 1, 64);
        int S = NR * 2 * 256 - 2 * acc;
        if (st) srow[55 * 256] = (short)S;
        s_acc += S; q_acc += S * S;
    }
}

// ---------------- Kernel 2: XNOR-popcount conv -> S (NHWC int16) + fused stats ----------------
// 2 blocks per (b,h) row: 128 o's x 2 j-halves. ~72 VGPRs of state per thread,
// cap 128 via launch_bounds(256,4) -> 4 waves/SIMD, no spills.
__global__ __launch_bounds__(256, 4) void kc_conv(
    const u64* __restrict__ xbits,
    const u64* __restrict__ wbits,
    short* __restrict__ S,           // [NPOS][256]
    int* __restrict__ ssum,
    unsigned long long* __restrict__ qsum)
{
    const int blk = blockIdx.x;        // [0, 2*NROW)
    const int row = blk >> 1;          // (b,h)
    const int ohalf = blk & 1;
    const int b = row / H_;
    const int h = row - b * H_;
    const int t = threadIdx.x;
    const int half = t & 1;            // channel-word half (j = 2*half, 2*half+1)
    const int o = ohalf * 128 + (t >> 1);

    __shared__ u64 tile[3 * W_ * 4];   // rows h-1..h+1 (clamped), [r][w][j]
    for (int idx = t; idx < 3 * W_ * 4; idx += 256) {
        int r = idx / (W_ * 4);
        int rem = idx - r * (W_ * 4);
        int hr = min(max(h - 1 + r, 0), H_ - 1);
        tile[idx] = xbits[((size_t)(b * HW + hr * W_)) * 4 + rem];
    }

    // this thread's 18 weight words (taps 0..8, 2 of 4 channel-words)
    u64 wr[18];
#pragma unroll
    for (int tap = 0; tap < 9; ++tap) {
        ulonglong2 v = *(const ulonglong2*)(wbits + (size_t)o * 36 + tap * 4 + 2 * half);
        wr[tap * 2] = v.x;
        wr[tap * 2 + 1] = v.y;
    }

    __syncthreads();

    const u64* t2 = tile + 2 * half;
    short* srow = S + ((size_t)(b * HW + h * W_)) * 256 + o;
    int s_acc = 0, q_acc = 0;
    const bool st = (half == 0);
    if (h == 0)        run_row2<1, 2>(t2, wr, srow, st, s_acc, q_acc);
    else if (h == 55)  run_row2<0, 1>(t2, wr, srow, st, s_acc, q_acc);
    else               run_row2<0, 2>(t2, wr, srow, st, s_acc, q_acc);

    if (st) {
        atomicAdd(&ssum[o], s_acc);
        atomicAdd(&qsum[o], (unsigned long long)(long long)q_acc);
    }
}

// ---------------- Kernel 3: finalize BN (per-block) + NHWC->NCHW apply + ReLU ----------------
__global__ __launch_bounds__(256) void kb_apply(
    const short* __restrict__ S,
    const int* __restrict__ ssum,
    const unsigned long long* __restrict__ qsum,
    const float* __restrict__ alpha,
    const float* __restrict__ gamma,
    const float* __restrict__ beta,
    float* __restrict__ out)
{
    const int blk = blockIdx.x;        // (b,h)
    const int b = blk / H_;
    const int h = blk - b * H_;
    const int tid = threadIdx.x;

    __shared__ float s_scale[256], s_shift[256];
    __shared__ short lds[W_ * 258];    // [p][c], padded row stride 258 shorts

    {   // per-channel BN finalize (cheap, recomputed per block)
        const int o = tid;
        const double N = (double)NPOS;
        double meanS = (double)ssum[o] / N;
        double varS = (double)qsum[o] / N - meanS * meanS;
        double a = (double)alpha[o];
        double rstd = 1.0 / sqrt(a * a * varS + 1e-5);
        double g = (double)gamma[o];
        s_scale[o] = (float)(g * a * rstd);
        s_shift[o] = (float)((double)beta[o] - g * a * meanS * rstd);
        // conv bias cancels exactly in training-mode BN
    }

    // coalesced copy in: row block is 56*256 shorts contiguous
    const u32* Sw = (const u32*)(S + ((size_t)(b * HW + h * W_)) * 256);
    for (int k = tid; k < W_ * 128; k += 256) {
        int p = k >> 7, cp = k & 127;
        *(u32*)&lds[p * 258 + cp * 2] = Sw[k];
    }
    __syncthreads();

    const int p = tid & 63;            // position within row
    const int cq = tid >> 6;           // channel-pair sub-group
    if (p < W_) {
        const size_t obase = (size_t)b * COUT * HW + (size_t)h * W_ + p;
#pragma unroll 4
        for (int it = 0; it < 32; ++it) {
            const int pr = it * 4 + cq;               // pair index, wave-uniform
            const u32 v = *(const u32*)&lds[p * 258 + pr * 2];
            const int c0 = 2 * pr, c1 = c0 + 1;
            const float f0 = fmaxf(fmaf((float)(short)(v & 0xFFFF), s_scale[c0], s_shift[c0]), 0.0f);
            const float f1 = fmaxf(fmaf((float)(short)(v >> 16),    s_scale[c1], s_shift[c1]), 0.0f);
            out[obase + (size_t)c0 * HW] = f0;
            out[obase + (size_t)c1 * HW] = f1;
        }
    }
}

extern "C" void kernel_launch(void* const* d_in, const int* in_sizes, int n_in,
                              void* d_out, int out_size, void* d_ws, size_t ws_size,
                              hipStream_t stream) {
    const float* x     = (const float*)d_in[0];   // [32,256,56,56]
    const float* wgt   = (const float*)d_in[1];   // [256,256,3,3]
    // d_in[2] = bias: cancels exactly in BN, unused
    const float* gamma = (const float*)d_in[3];
    const float* beta  = (const float*)d_in[4];
    float* out = (float*)d_out;

    char* ws = (char*)d_ws;
    u64*   wbits = (u64*)(ws + 0);
    float* alpha = (float*)(ws + 73728);
    int*   ssum  = (int*)(ws + 74752);
    unsigned long long* qsum = (unsigned long long*)(ws + 75776);
    u64*   xbits = (u64*)(ws + 79872);
    short* Sarr  = (short*)(ws + 3291136);

    k_prep<<<NPACKBLK + 256, 256, 0, stream>>>(x, wgt, xbits, wbits, alpha, ssum, qsum);
    kc_conv<<<2 * NROW, 256, 0, stream>>>(xbits, wbits, Sarr, ssum, qsum);
    kb_apply<<<NROW, 256, 0, stream>>>(Sarr, ssum, qsum, alpha, gamma, beta, out);
}

// Round 5
// 330.214 us; speedup vs baseline: 1.0687x; 1.0687x over previous
//
#include <hip/hip_runtime.h>
#include <stdint.h>

typedef unsigned long long u64;
typedef unsigned int u32;

#define B_    32
#define CIN   256
#define COUT  256
#define H_    56
#define W_    56
#define HW    3136            // H_*W_
#define NPOS  100352          // B_*HW
#define NROW  1792            // B_*H_
#define NPACKBLK 784          // (NPOS/2/256) * 4 j-chunks

// ---- workspace layout (bytes) ----
// 0       : wbits u64[256*36]        73728
// 73728   : alpha f32[256]           1024
// 74752   : ssum  i32[256]           1024
// 75776   : qsum  u64[256]           2048
// 79872   : xbits u64[NPOS*4]        3211264   (ends 3291136)
// 3291136 : S     s16[NPOS*256] NHWC 51380224

// ---------------- Kernel 1: prep (x bitpack ∪ weight prep), grid-partitioned ----------------
__global__ __launch_bounds__(256) void k_prep(
    const float* __restrict__ x,     // [B, C, H, W]
    const float* __restrict__ wgt,   // [O=256, I=256, 3, 3]
    u64* __restrict__ xbits,         // [NPOS][4]
    u64* __restrict__ wbits,         // [O][9 taps][4 words]
    float* __restrict__ alpha,
    int* __restrict__ ssum,
    unsigned long long* __restrict__ qsum)
{
    const int tid = threadIdx.x;

    if (blockIdx.x < NPACKBLK) {
        // ---- pack sign(x): 2 positions per thread via float2, 8 loads in flight ----
        const int j = blockIdx.x / 196;                  // channel chunk
        const int p2 = (blockIdx.x - j * 196) * 256 + tid;
        const int pos0 = p2 * 2;                          // even; HW even -> no b crossing
        const int b = pos0 / HW;
        const int hw = pos0 - b * HW;
        const float* xp = x + (size_t)b * CIN * HW + (size_t)j * 64 * HW + hw;
        u64 b0 = 0, b1 = 0;
#pragma unroll 8
        for (int k = 0; k < 64; ++k) {
            const float2 v = *(const float2*)(xp + (size_t)k * HW);
            b0 |= (u64)(v.x > 0.0f) << k;
            b1 |= (u64)(v.y > 0.0f) << k;
        }
        xbits[(size_t)pos0 * 4 + j] = b0;
        xbits[(size_t)(pos0 + 1) * 4 + j] = b1;
        return;
    }

    // ---- weight prep: mean-center, clip, alpha, bitpack; zero stats ----
    const int o = blockIdx.x - NPACKBLK;
    const int i = tid;                 // input channel
    const int wave = i >> 6, lane = i & 63;
    __shared__ float sred[4][12];

    if (i == 0) { ssum[o] = 0; qsum[o] = 0ULL; }

    float w9[9];
#pragma unroll
    for (int t = 0; t < 9; ++t) w9[t] = wgt[(o * 256 + i) * 9 + t];

    float m[9];
#pragma unroll
    for (int t = 0; t < 9; ++t) m[t] = w9[t];
#pragma unroll
    for (int s = 1; s < 64; s <<= 1)
#pragma unroll
        for (int t = 0; t < 9; ++t) m[t] += __shfl_xor(m[t], s, 64);
    if (lane == 0) {
#pragma unroll
        for (int t = 0; t < 9; ++t) sred[wave][t] = m[t];
    }
    __syncthreads();
#pragma unroll
    for (int t = 0; t < 9; ++t)
        m[t] = (sred[0][t] + sred[1][t] + sred[2][t] + sred[3][t]) * (1.0f / 256.0f);

    float wc[9];
    float asum = 0.0f;
#pragma unroll
    for (int t = 0; t < 9; ++t) {
        float v = w9[t] - m[t];
        v = fminf(fmaxf(v, -1.0f), 1.0f);
        wc[t] = v;
        asum += fabsf(v);
    }
#pragma unroll
    for (int s = 1; s < 64; s <<= 1) asum += __shfl_xor(asum, s, 64);
    __syncthreads();
    if (lane == 0) sred[wave][9] = asum;
    __syncthreads();
    if (i == 0)
        alpha[o] = (sred[0][9] + sred[1][9] + sred[2][9] + sred[3][9]) * (1.0f / 2304.0f);

#pragma unroll
    for (int t = 0; t < 9; ++t) {
        u64 bb = __ballot(wc[t] > 0.0f);   // bit=1 <-> +1
        if (lane == 0) wbits[o * 36 + t * 4 + wave] = bb;
    }
}

// ---------------- conv row processor: lane-pair split, 4-slot register ring ----------------
// Each thread handles 2 of the 4 channel-words (jj=0,1 at t2 = tile + 2*half).
// FILL loads a column into ring slot; PIN (empty asm) forces the values to stay
// in VGPRs — the compiler cannot rematerialize an asm output from LDS.
// Schedule per output w: FILL(w+2) issued, COMP(w) (uses pinned w-1..w+1), PIN(w+2):
// ds_read latency hides under the ~72 popcount VALU ops of COMP.
template<int R0, int R1>
__device__ __forceinline__ void run_row2(
    const u64* __restrict__ t2,
    const u64* wr,                   // 18 words: [tap 0..8][jj 0..1] (taps R0*3..)
    short* __restrict__ srow,
    const bool st,
    int& s_acc, int& q_acc)
{
    constexpr int NR = R1 - R0 + 1;
    u64 xc[4][NR][2];

#define FILL(col, slot) { \
    _Pragma("unroll") \
    for (int r = 0; r < NR; ++r) { \
        const ulonglong2 v = *(const ulonglong2*)&t2[((R0 + r) * 56 + (col)) * 4]; \
        xc[slot][r][0] = v.x; xc[slot][r][1] = v.y; } }

#define PIN(slot) { \
    _Pragma("unroll") \
    for (int r = 0; r < NR; ++r) { \
        asm volatile("" : "+v"(xc[slot][r][0])); \
        asm volatile("" : "+v"(xc[slot][r][1])); } }

#define TAPACC(slot, r, kw) \
    acc += (int)__popcll(xc[slot][r][0] ^ wr[((R0 + r) * 3 + (kw)) * 2 + 0]) \
         + (int)__popcll(xc[slot][r][1] ^ wr[((R0 + r) * 3 + (kw)) * 2 + 1]);

#define COMPW(sm, s0, sp, SROWOFF) { \
    int acc = 0; \
    _Pragma("unroll") \
    for (int r = 0; r < NR; ++r) { TAPACC(sm, r, 0) TAPACC(s0, r, 1) TAPACC(sp, r, 2) } \
    acc += __shfl_xor(acc, 1, 64); \
    const int Sv = NR * 3 * 256 - 2 * acc; \
    if (st) srow[(SROWOFF) * 256] = (short)Sv; \
    s_acc += Sv; q_acc += Sv * Sv; }

    // prologue: cols 0,1 resident; col 2 in flight
    FILL(0, 0) FILL(1, 1) FILL(2, 2) PIN(0) PIN(1)

    // w = 0 : kw in {1,2} -> cols 0,1 (slots 0,1)
    {
        int acc = 0;
#pragma unroll
        for (int r = 0; r < NR; ++r) { TAPACC(0, r, 1) TAPACC(1, r, 2) }
        acc += __shfl_xor(acc, 1, 64);
        const int Sv = NR * 2 * 256 - 2 * acc;
        if (st) srow[0] = (short)Sv;
        s_acc += Sv; q_acc += Sv * Sv;
    }
    FILL(3, 3) PIN(2)

    // w = 1 : cols 0,1,2 (slots 0,1,2)
    COMPW(0, 1, 2, 1) PIN(3)

    // main: w = 2..53, 13 x 4-unrolled; slot(col) = col & 3
    for (int wb = 2; wb <= 50; wb += 4) {
        FILL(wb + 2, 0) COMPW(1, 2, 3, wb + 0) PIN(0)
        FILL(wb + 3, 1) COMPW(2, 3, 0, wb + 1) PIN(1)
        FILL(wb + 4, 2) COMPW(3, 0, 1, wb + 2) PIN(2)
        FILL(wb + 5, 3) COMPW(0, 1, 2, wb + 3) PIN(3)
    }

    // w = 54 : cols 53,54,55 (slots 1,2,3)
    COMPW(1, 2, 3, 54)

    // w = 55 : kw in {0,1} -> cols 54,55 (slots 2,3)
    {
        int acc = 0;
#pragma unroll
        for (int r = 0; r < NR; ++r) { TAPACC(2, r, 0) TAPACC(3, r, 1) }
        acc += __shfl_xor(acc, 1, 64);
        const int Sv = NR * 2 * 256 - 2 * acc;
        if (st) srow[55 * 256] = (short)Sv;
        s_acc += Sv; q_acc += Sv * Sv;
    }

#undef FILL
#undef PIN
#undef TAPACC
#undef COMPW
}

// ---------------- Kernel 2: XNOR-popcount conv -> S (NHWC int16) + fused stats ----------------
__global__ __launch_bounds__(256, 4) void kc_conv(
    const u64* __restrict__ xbits,
    const u64* __restrict__ wbits,
    short* __restrict__ S,           // [NPOS][256]
    int* __restrict__ ssum,
    unsigned long long* __restrict__ qsum)
{
    const int blk = blockIdx.x;        // [0, 2*NROW)
    const int row = blk >> 1;          // (b,h)
    const int ohalf = blk & 1;
    const int b = row / H_;
    const int h = row - b * H_;
    const int t = threadIdx.x;
    const int half = t & 1;            // channel-word half (jj covers j = 2*half+{0,1})
    const int o = ohalf * 128 + (t >> 1);

    __shared__ u64 tile[3 * W_ * 4];   // rows h-1..h+1 (clamped), [r][w][j]
    for (int idx = t; idx < 3 * W_ * 4; idx += 256) {
        int r = idx / (W_ * 4);
        int rem = idx - r * (W_ * 4);
        int hr = min(max(h - 1 + r, 0), H_ - 1);
        tile[idx] = xbits[((size_t)(b * HW + hr * W_)) * 4 + rem];
    }

    // this thread's 18 weight words, register-pinned
    u64 wr[18];
#pragma unroll
    for (int tap = 0; tap < 9; ++tap) {
        ulonglong2 v = *(const ulonglong2*)(wbits + (size_t)o * 36 + tap * 4 + 2 * half);
        wr[tap * 2] = v.x;
        wr[tap * 2 + 1] = v.y;
    }
#pragma unroll
    for (int i = 0; i < 18; ++i) asm volatile("" : "+v"(wr[i]));

    __syncthreads();

    const u64* t2 = tile + 2 * half;
    short* srow = S + ((size_t)(b * HW + h * W_)) * 256 + o;
    int s_acc = 0, q_acc = 0;
    const bool st = (half == 0);
    if (h == 0)        run_row2<1, 2>(t2, wr, srow, st, s_acc, q_acc);
    else if (h == 55)  run_row2<0, 1>(t2, wr, srow, st, s_acc, q_acc);
    else               run_row2<0, 2>(t2, wr, srow, st, s_acc, q_acc);

    if (st) {
        atomicAdd(&ssum[o], s_acc);
        atomicAdd(&qsum[o], (unsigned long long)(long long)q_acc);
    }
}

// ---------------- Kernel 3: BN finalize + NHWC->NCHW transpose + ReLU ----------------
// Block = (b, c64-group, p-seventh). Reads: full-128B-line coalesced. Stores:
// 256B contiguous per wave. LDS transpose tile 64p x 64c, stride 66 shorts.
__global__ __launch_bounds__(256) void kb_apply(
    const short* __restrict__ S,
    const int* __restrict__ ssum,
    const unsigned long long* __restrict__ qsum,
    const float* __restrict__ alpha,
    const float* __restrict__ gamma,
    const float* __restrict__ beta,
    float* __restrict__ out)
{
    const int blk = blockIdx.x;              // ((b*4 + cg)*7 + ps)
    const int ps = blk % 7;
    const int bcg = blk / 7;
    const int cg = bcg & 3;
    const int b = bcg >> 2;
    const int c0 = cg * 64;
    const int pbase = ps * 448;
    const int tid = threadIdx.x;

    __shared__ float s_scale[64], s_shift[64];
    __shared__ u32 lds[64 * 33];             // [p][cpair], stride 33 dwords

    if (tid < 64) {                          // BN finalize for this c-group
        const int o = c0 + tid;
        const double N = (double)NPOS;
        double meanS = (double)ssum[o] / N;
        double varS = (double)qsum[o] / N - meanS * meanS;
        double a = (double)alpha[o];
        double rstd = 1.0 / sqrt(a * a * varS + 1e-5);
        double g = (double)gamma[o];
        s_scale[tid] = (float)(g * a * rstd);
        s_shift[tid] = (float)((double)beta[o] - g * a * meanS * rstd);
        // conv bias cancels exactly in training-mode BN
    }
    __syncthreads();

    for (int chunk = 0; chunk < 7; ++chunk) {
        const int p0 = pbase + chunk * 64;

        // read 64p x 64c: 2048 u32, 8 per thread, full-line coalesced
        const u32* Sp = (const u32*)(S + ((size_t)b * HW + p0) * 256 + c0);
#pragma unroll
        for (int k = 0; k < 8; ++k) {
            const int idx = tid + k * 256;   // 0..2047
            const int p = idx >> 5, cp = idx & 31;
            lds[p * 33 + cp] = Sp[p * 128 + cp];
        }
        __syncthreads();

        // write: lanes = consecutive p -> 256B contiguous stores
        const int pl = tid & 63;
        const int ch4 = tid >> 6;            // 4 groups of 16 channels
        const short* lss = (const short*)lds;
#pragma unroll
        for (int cc = 0; cc < 16; ++cc) {
            const int c = ch4 * 16 + cc;
            const float f = fmaxf(fmaf((float)lss[pl * 66 + c], s_scale[c], s_shift[c]), 0.0f);
            out[((size_t)(b * COUT + c0 + c)) * HW + p0 + pl] = f;
        }
        __syncthreads();
    }
}

extern "C" void kernel_launch(void* const* d_in, const int* in_sizes, int n_in,
                              void* d_out, int out_size, void* d_ws, size_t ws_size,
                              hipStream_t stream) {
    const float* x     = (const float*)d_in[0];   // [32,256,56,56]
    const float* wgt   = (const float*)d_in[1];   // [256,256,3,3]
    // d_in[2] = bias: cancels exactly in BN, unused
    const float* gamma = (const float*)d_in[3];
    const float* beta  = (const float*)d_in[4];
    float* out = (float*)d_out;

    char* ws = (char*)d_ws;
    u64*   wbits = (u64*)(ws + 0);
    float* alpha = (float*)(ws + 73728);
    int*   ssum  = (int*)(ws + 74752);
    unsigned long long* qsum = (unsigned long long*)(ws + 75776);
    u64*   xbits = (u64*)(ws + 79872);
    short* Sarr  = (short*)(ws + 3291136);

    k_prep<<<NPACKBLK + 256, 256, 0, stream>>>(x, wgt, xbits, wbits, alpha, ssum, qsum);
    kc_conv<<<2 * NROW, 256, 0, stream>>>(xbits, wbits, Sarr, ssum, qsum);
    kb_apply<<<32 * 4 * 7, 256, 0, stream>>>(Sarr, ssum, qsum, alpha, gamma, beta, out);
}

// Round 6
// 292.322 us; speedup vs baseline: 1.2073x; 1.1296x over previous
//
#include <hip/hip_runtime.h>
#include <stdint.h>

typedef unsigned long long u64;
typedef unsigned int u32;
typedef int v4i __attribute__((ext_vector_type(4)));
typedef int v16i __attribute__((ext_vector_type(16)));

#define B_    32
#define CIN   256
#define COUT  256
#define H_    56
#define W_    56
#define HW    3136            // H_*W_
#define NPOS  100352          // B_*HW
#define NROW  1792            // B_*H_
#define NPACKBLK 784          // (NPOS/2/256) * 4 j-chunks

// ---- workspace layout (bytes) ----
// 0        : Bfrag i8[72*8*64*16]     589824   (MFMA B-operand, fragment-order)
// 589824   : alpha f32[256]           1024
// 590848   : ssum  i32[256]           1024
// 591872   : qsum  u64[256]           2048
// 593920   : xbits u64[NPOS*4]        3211264  (ends 3805184)
// 3805184  : S     s16[NPOS*256] NHWC 51380224 (ends 55185408)

// ---------------- Kernel 1: prep (x bitpack ∪ weight prep), grid-partitioned ----------------
__global__ __launch_bounds__(256) void k_prep(
    const float* __restrict__ x,     // [B, C, H, W]
    const float* __restrict__ wgt,   // [O=256, I=256, 3, 3]
    u64* __restrict__ xbits,         // [NPOS][4]
    int8_t* __restrict__ Bfrag,      // [kk=72][nt=8][lane=64][16]
    float* __restrict__ alpha,
    int* __restrict__ ssum,
    unsigned long long* __restrict__ qsum)
{
    const int tid = threadIdx.x;

    if (blockIdx.x < NPACKBLK) {
        // ---- pack sign(x): 2 positions per thread via float2 ----
        const int j = blockIdx.x / 196;                  // channel chunk
        const int p2 = (blockIdx.x - j * 196) * 256 + tid;
        const int pos0 = p2 * 2;                          // even; HW even -> no b crossing
        const int b = pos0 / HW;
        const int hw = pos0 - b * HW;
        const float* xp = x + (size_t)b * CIN * HW + (size_t)j * 64 * HW + hw;
        u64 b0 = 0, b1 = 0;
#pragma unroll 8
        for (int k = 0; k < 64; ++k) {
            const float2 v = *(const float2*)(xp + (size_t)k * HW);
            b0 |= (u64)(v.x > 0.0f) << k;
            b1 |= (u64)(v.y > 0.0f) << k;
        }
        xbits[(size_t)pos0 * 4 + j] = b0;
        xbits[(size_t)(pos0 + 1) * 4 + j] = b1;
        return;
    }

    // ---- weight prep: mean-center, clip, alpha, Bfrag bytes; zero stats ----
    const int o = blockIdx.x - NPACKBLK;
    const int i = tid;                 // input channel
    const int wave = i >> 6, lane = i & 63;
    __shared__ float sred[4][12];

    if (i == 0) { ssum[o] = 0; qsum[o] = 0ULL; }

    float w9[9];
#pragma unroll
    for (int t = 0; t < 9; ++t) w9[t] = wgt[(o * 256 + i) * 9 + t];

    float m[9];
#pragma unroll
    for (int t = 0; t < 9; ++t) m[t] = w9[t];
#pragma unroll
    for (int s = 1; s < 64; s <<= 1)
#pragma unroll
        for (int t = 0; t < 9; ++t) m[t] += __shfl_xor(m[t], s, 64);
    if (lane == 0) {
#pragma unroll
        for (int t = 0; t < 9; ++t) sred[wave][t] = m[t];
    }
    __syncthreads();
#pragma unroll
    for (int t = 0; t < 9; ++t)
        m[t] = (sred[0][t] + sred[1][t] + sred[2][t] + sred[3][t]) * (1.0f / 256.0f);

    float wc[9];
    float asum = 0.0f;
#pragma unroll
    for (int t = 0; t < 9; ++t) {
        float v = w9[t] - m[t];
        v = fminf(fmaxf(v, -1.0f), 1.0f);
        wc[t] = v;
        asum += fabsf(v);
    }
#pragma unroll
    for (int s = 1; s < 64; s <<= 1) asum += __shfl_xor(asum, s, 64);
    __syncthreads();
    if (lane == 0) sred[wave][9] = asum;
    __syncthreads();
    if (i == 0)
        alpha[o] = (sred[0][9] + sred[1][9] + sred[2][9] + sred[3][9]) * (1.0f / 2304.0f);

    // Bfrag[kk][nt][l][j]: value = sign(wc) for k = kk*32 + (l>>5)*16 + j,
    // tap = k>>8, c = k&255; n = nt*32 + (l&31) = o.
    // Thread i (=c) writes 9 bytes (one per tap):
    //   kk = t*8 + (i>>5); l = ((i>>4)&1)*32 + (o&31); j = i&15.
#pragma unroll
    for (int t = 0; t < 9; ++t) {
        const int8_t sv = (wc[t] > 0.0f) ? (int8_t)1 : (int8_t)-1;
        const size_t addr =
            ((size_t)((t * 8 + (i >> 5)) * 8 + (o >> 5)) * 64
             + (size_t)(((i >> 4) & 1) * 32 + (o & 31))) * 16 + (i & 15);
        Bfrag[addr] = sv;
    }
}

// ---------------- Kernel 2: implicit-GEMM i8 MFMA conv -> S (NHWC s16) + stats ----------------
// Block = (b,h): M=64 positions (56 valid), N=256 channels, K=2304 (72 steps of 32).
// A staged in LDS as ±1 bytes expanded from xbits, rows h-1..h+1 zero-padded,
// 16B granules rotated by column to break the 256B-stride bank pattern.
// B streamed from Bfrag (fragment-order, L2-resident, 16B/lane coalesced).
#define MFMA_I8(acc, a, b) \
    asm volatile("v_mfma_i32_32x32x32_i8 %0, %1, %2, %0" : "+a"(acc) : "v"(a), "v"(b))

__global__ __launch_bounds__(256, 3) void kc_mfma(
    const u64* __restrict__ xbits,
    const int8_t* __restrict__ Bfrag,
    short* __restrict__ S,           // [NPOS][256]
    int* __restrict__ ssum,
    unsigned long long* __restrict__ qsum)
{
    const int blk = blockIdx.x;        // (b,h)
    const int b = blk / H_;
    const int h = blk - b * H_;
    const int tid = threadIdx.x;

    // LDS A-tile: 3 rows x 66 cols x 256 ch bytes; granule g of col wp stored
    // at slot (g+wp)&15.  Cols: wp = w_in+1 (wp 0 and 57 are zero padding;
    // wp 58..65 only feed discarded M-padding lanes).
    __shared__ u32 ldsb[3 * 66 * 64];

    for (int it = tid; it < 3 * 58 * 16; it += 256) {
        const int r = it / 928;              // 58*16
        const int rem = it - r * 928;
        const int wp = rem >> 4;
        const int g = rem & 15;
        const int hr = h - 1 + r;
        const int w_in = wp - 1;
        const bool inb = (hr >= 0) && (hr < H_) && (w_in >= 0) && (w_in < W_);
        u32 chunk16 = 0;
        if (inb) {
            const u64 word = xbits[((size_t)(b * HW + hr * W_ + w_in)) * 4 + (g >> 2)];
            chunk16 = (u32)(word >> ((g & 3) * 16)) & 0xFFFFu;
        }
        u32 out4[4];
#pragma unroll
        for (int d = 0; d < 4; ++d) {
            const u32 nib = (chunk16 >> (4 * d)) & 0xFu;
            const u32 m1 = (nib * 0x00204081u) & 0x01010101u;   // bit u -> byte u
            const u32 inv = m1 ^ 0x01010101u;
            out4[d] = inb ? (0x01010101u ^ (inv * 0xFEu)) : 0u; // 1->+1, 0->-1, OOB->0
        }
        const int gs = (g + wp) & 15;
        u32* dst = &ldsb[((r * 66 + wp) << 6) + gs * 4];
        dst[0] = out4[0]; dst[1] = out4[1]; dst[2] = out4[2]; dst[3] = out4[3];
    }
    __syncthreads();

    const int m0 = tid & 31;           // M row within tile
    const int lh = (tid >> 5) & 1;     // k-half selector
    const int wv = tid >> 6;           // wave id: N cols 64*wv .. 64*wv+63
    const int8_t* smem = (const int8_t*)ldsb;
    const int8_t* Bp = Bfrag + (size_t)(tid & 63) * 16;

    auto ldA = [&](int kk, int mt) -> v4i {
        const int tap = kk >> 3, s = kk & 7;
        const int dh = tap / 3;
        const int dw = tap - dh * 3;
        const int wpm = mt * 32 + m0 + dw;
        const int gs = (2 * s + lh + wpm) & 15;
        const int addr = ((dh * 66 + wpm) << 8) + (gs << 4);
        return *(const v4i*)(smem + addr);
    };
    auto ldB = [&](int kk, int ntl) -> v4i {
        const size_t off = (size_t)((kk * 8) + wv * 2 + ntl) * 1024;
        return *(const v4i*)(Bp + off);
    };

    v16i acc00 = {0}, acc01 = {0}, acc10 = {0}, acc11 = {0};

    v4i a0 = ldA(0, 0), a1 = ldA(0, 1);
    v4i b0 = ldB(0, 0), b1 = ldB(0, 1);
    v4i a0n, a1n, b0n, b1n;

    for (int kk = 0; kk < 72; kk += 2) {
        a0n = ldA(kk + 1, 0); a1n = ldA(kk + 1, 1);
        b0n = ldB(kk + 1, 0); b1n = ldB(kk + 1, 1);
        MFMA_I8(acc00, a0, b0); MFMA_I8(acc01, a0, b1);
        MFMA_I8(acc10, a1, b0); MFMA_I8(acc11, a1, b1);
        if (kk + 2 < 72) {
            a0 = ldA(kk + 2, 0); a1 = ldA(kk + 2, 1);
            b0 = ldB(kk + 2, 0); b1 = ldB(kk + 2, 1);
        }
        MFMA_I8(acc00, a0n, b0n); MFMA_I8(acc01, a0n, b1n);
        MFMA_I8(acc10, a1n, b0n); MFMA_I8(acc11, a1n, b1n);
    }

    // drain MFMA pipe before AGPR reads (compiler is blind to asm latency)
    asm volatile("s_nop 7\n\ts_nop 7\n\ts_nop 7"
                 : "+a"(acc00), "+a"(acc01), "+a"(acc10), "+a"(acc11));

    // C/D layout: n = nt*32 + (lane&31); m = mt*32 + (reg&3) + 8*(reg>>2) + 4*lh
    const int n0 = wv * 64 + m0;
    const int n1 = n0 + 32;
    const int rowbase = b * HW + h * W_;
    int s0 = 0, s1 = 0, q0 = 0, q1 = 0;

#pragma unroll
    for (int reg = 0; reg < 16; ++reg) {     // mt = 0: all rows valid (m<32)
        const int m = (reg & 3) + ((reg >> 2) << 3) + (lh << 2);
        const int v0 = acc00[reg], v1 = acc01[reg];
        s0 += v0; q0 += v0 * v0; s1 += v1; q1 += v1 * v1;
        S[(size_t)(rowbase + m) * 256 + n0] = (short)v0;
        S[(size_t)(rowbase + m) * 256 + n1] = (short)v1;
    }
#pragma unroll
    for (int reg = 0; reg < 12; ++reg) {     // mt = 1: rows 32..55 only (reg<12)
        const int m = 32 + (reg & 3) + ((reg >> 2) << 3) + (lh << 2);
        const int v0 = acc10[reg], v1 = acc11[reg];
        s0 += v0; q0 += v0 * v0; s1 += v1; q1 += v1 * v1;
        S[(size_t)(rowbase + m) * 256 + n0] = (short)v0;
        S[(size_t)(rowbase + m) * 256 + n1] = (short)v1;
    }

    s0 += __shfl_xor(s0, 32, 64); q0 += __shfl_xor(q0, 32, 64);
    s1 += __shfl_xor(s1, 32, 64); q1 += __shfl_xor(q1, 32, 64);
    if (lh == 0) {
        atomicAdd(&ssum[n0], s0);
        atomicAdd(&qsum[n0], (unsigned long long)(long long)q0);
        atomicAdd(&ssum[n1], s1);
        atomicAdd(&qsum[n1], (unsigned long long)(long long)q1);
    }
}

// ---------------- Kernel 3: BN finalize + NHWC->NCHW transpose + ReLU ----------------
__global__ __launch_bounds__(256) void kb_apply(
    const short* __restrict__ S,
    const int* __restrict__ ssum,
    const unsigned long long* __restrict__ qsum,
    const float* __restrict__ alpha,
    const float* __restrict__ gamma,
    const float* __restrict__ beta,
    float* __restrict__ out)
{
    const int blk = blockIdx.x;              // ((b*4 + cg)*7 + ps)
    const int ps = blk % 7;
    const int bcg = blk / 7;
    const int cg = bcg & 3;
    const int b = bcg >> 2;
    const int c0 = cg * 64;
    const int pbase = ps * 448;
    const int tid = threadIdx.x;

    __shared__ float s_scale[64], s_shift[64];
    __shared__ u32 lds[64 * 33];             // [p][cpair], stride 33 dwords

    if (tid < 64) {                          // BN finalize for this c-group
        const int o = c0 + tid;
        const double N = (double)NPOS;
        double meanS = (double)ssum[o] / N;
        double varS = (double)qsum[o] / N - meanS * meanS;
        double a = (double)alpha[o];
        double rstd = 1.0 / sqrt(a * a * varS + 1e-5);
        double g = (double)gamma[o];
        s_scale[tid] = (float)(g * a * rstd);
        s_shift[tid] = (float)((double)beta[o] - g * a * meanS * rstd);
        // conv bias cancels exactly in training-mode BN
    }
    __syncthreads();

    for (int chunk = 0; chunk < 7; ++chunk) {
        const int p0 = pbase + chunk * 64;

        // read 64p x 64c: 2048 u32, 8 per thread, full-line coalesced
        const u32* Sp = (const u32*)(S + ((size_t)b * HW + p0) * 256 + c0);
#pragma unroll
        for (int k = 0; k < 8; ++k) {
            const int idx = tid + k * 256;   // 0..2047
            const int p = idx >> 5, cp = idx & 31;
            lds[p * 33 + cp] = Sp[p * 128 + cp];
        }
        __syncthreads();

        // write: lanes = consecutive p -> 256B contiguous stores
        const int pl = tid & 63;
        const int ch4 = tid >> 6;            // 4 groups of 16 channels
        const short* lss = (const short*)lds;
#pragma unroll
        for (int cc = 0; cc < 16; ++cc) {
            const int c = ch4 * 16 + cc;
            const float f = fmaxf(fmaf((float)lss[pl * 66 + c], s_scale[c], s_shift[c]), 0.0f);
            out[((size_t)(b * COUT + c0 + c)) * HW + p0 + pl] = f;
        }
        __syncthreads();
    }
}

extern "C" void kernel_launch(void* const* d_in, const int* in_sizes, int n_in,
                              void* d_out, int out_size, void* d_ws, size_t ws_size,
                              hipStream_t stream) {
    const float* x     = (const float*)d_in[0];   // [32,256,56,56]
    const float* wgt   = (const float*)d_in[1];   // [256,256,3,3]
    // d_in[2] = bias: cancels exactly in BN, unused
    const float* gamma = (const float*)d_in[3];
    const float* beta  = (const float*)d_in[4];
    float* out = (float*)d_out;

    char* ws = (char*)d_ws;
    int8_t* Bfrag = (int8_t*)(ws + 0);
    float* alpha = (float*)(ws + 589824);
    int*   ssum  = (int*)(ws + 590848);
    unsigned long long* qsum = (unsigned long long*)(ws + 591872);
    u64*   xbits = (u64*)(ws + 593920);
    short* Sarr  = (short*)(ws + 3805184);

    k_prep<<<NPACKBLK + 256, 256, 0, stream>>>(x, wgt, xbits, Bfrag, alpha, ssum, qsum);
    kc_mfma<<<NROW, 256, 0, stream>>>(xbits, Bfrag, Sarr, ssum, qsum);
    kb_apply<<<32 * 4 * 7, 256, 0, stream>>>(Sarr, ssum, qsum, alpha, gamma, beta, out);
}

// Round 7
// 277.636 us; speedup vs baseline: 1.2711x; 1.0529x over previous
//
#include <hip/hip_runtime.h>
#include <stdint.h>

typedef unsigned long long u64;
typedef unsigned int u32;
typedef int v4i __attribute__((ext_vector_type(4)));
typedef int v16i __attribute__((ext_vector_type(16)));

#define B_    32
#define CIN   256
#define COUT  256
#define H_    56
#define W_    56
#define HW    3136            // H_*W_
#define NPOS  100352          // B_*HW
#define NROW  1792            // B_*H_
#define NPACKBLK 784          // (NPOS/2/256) * 4 j-chunks

// ---- workspace layout (bytes) ----
// 0        : Bfrag i8[72*8*64*16]     589824   (MFMA B-operand, fragment-order)
// 589824   : alpha f32[256]           1024
// 590848   : ssum  i32[256]           1024
// 591872   : qsum  u64[256]           2048
// 593920   : xbits u64[NPOS*4]        3211264  (ends 3805184)
// 3805184  : S     s16[NPOS*256] NHWC 51380224 (ends 55185408)

// ---------------- Kernel 1: prep (x bitpack ∪ weight prep), grid-partitioned ----------------
__global__ __launch_bounds__(256) void k_prep(
    const float* __restrict__ x,     // [B, C, H, W]
    const float* __restrict__ wgt,   // [O=256, I=256, 3, 3]
    u64* __restrict__ xbits,         // [NPOS][4]
    int8_t* __restrict__ Bfrag,      // [kk=72][nt=8][lane=64][16]
    float* __restrict__ alpha,
    int* __restrict__ ssum,
    unsigned long long* __restrict__ qsum)
{
    const int tid = threadIdx.x;

    if (blockIdx.x < NPACKBLK) {
        // ---- pack sign(x): 2 positions per thread via float2 ----
        const int j = blockIdx.x / 196;                  // channel chunk
        const int p2 = (blockIdx.x - j * 196) * 256 + tid;
        const int pos0 = p2 * 2;                          // even; HW even -> no b crossing
        const int b = pos0 / HW;
        const int hw = pos0 - b * HW;
        const float* xp = x + (size_t)b * CIN * HW + (size_t)j * 64 * HW + hw;
        u64 b0 = 0, b1 = 0;
#pragma unroll 8
        for (int k = 0; k < 64; ++k) {
            const float2 v = *(const float2*)(xp + (size_t)k * HW);
            b0 |= (u64)(v.x > 0.0f) << k;
            b1 |= (u64)(v.y > 0.0f) << k;
        }
        xbits[(size_t)pos0 * 4 + j] = b0;
        xbits[(size_t)(pos0 + 1) * 4 + j] = b1;
        return;
    }

    // ---- weight prep: mean-center, clip, alpha, Bfrag bytes; zero stats ----
    const int o = blockIdx.x - NPACKBLK;
    const int i = tid;                 // input channel
    const int wave = i >> 6, lane = i & 63;
    __shared__ float sred[4][12];

    if (i == 0) { ssum[o] = 0; qsum[o] = 0ULL; }

    float w9[9];
#pragma unroll
    for (int t = 0; t < 9; ++t) w9[t] = wgt[(o * 256 + i) * 9 + t];

    float m[9];
#pragma unroll
    for (int t = 0; t < 9; ++t) m[t] = w9[t];
#pragma unroll
    for (int s = 1; s < 64; s <<= 1)
#pragma unroll
        for (int t = 0; t < 9; ++t) m[t] += __shfl_xor(m[t], s, 64);
    if (lane == 0) {
#pragma unroll
        for (int t = 0; t < 9; ++t) sred[wave][t] = m[t];
    }
    __syncthreads();
#pragma unroll
    for (int t = 0; t < 9; ++t)
        m[t] = (sred[0][t] + sred[1][t] + sred[2][t] + sred[3][t]) * (1.0f / 256.0f);

    float wc[9];
    float asum = 0.0f;
#pragma unroll
    for (int t = 0; t < 9; ++t) {
        float v = w9[t] - m[t];
        v = fminf(fmaxf(v, -1.0f), 1.0f);
        wc[t] = v;
        asum += fabsf(v);
    }
#pragma unroll
    for (int s = 1; s < 64; s <<= 1) asum += __shfl_xor(asum, s, 64);
    __syncthreads();
    if (lane == 0) sred[wave][9] = asum;
    __syncthreads();
    if (i == 0)
        alpha[o] = (sred[0][9] + sred[1][9] + sred[2][9] + sred[3][9]) * (1.0f / 2304.0f);

    // Bfrag[kk][nt][l][j]: value = sign(wc) for k = kk*32 + (l>>5)*16 + j,
    // tap = k>>8, c = k&255; n = nt*32 + (l&31) = o.
#pragma unroll
    for (int t = 0; t < 9; ++t) {
        const int8_t sv = (wc[t] > 0.0f) ? (int8_t)1 : (int8_t)-1;
        const size_t addr =
            ((size_t)((t * 8 + (i >> 5)) * 8 + (o >> 5)) * 64
             + (size_t)(((i >> 4) & 1) * 32 + (o & 31))) * 16 + (i & 15);
        Bfrag[addr] = sv;
    }
}

// ---------------- Kernel 2: implicit-GEMM i8 MFMA conv -> S (NHWC s16) + stats ----------------
// Block = (b,h): M=64 positions (56 valid), N=256 channels, K=2304 (72 steps of 32).
// A staged in LDS as ±1 bytes (58 cols: wp=0 and 57 are zero pad; M-pad rows
// clamp to col 57 — results discarded). Granule rotation (g+wp)&15 breaks the
// 256B-stride bank pattern. B streamed from Bfrag (fragment-order, L2-resident).
// K-loop fully unrolled: tap/dh/dw/gs constant-fold; explicit double-buffer regs.
#define MFMA_I8(acc, a, b) \
    asm volatile("v_mfma_i32_32x32x32_i8 %0, %1, %2, %0" : "+a"(acc) : "v"(a), "v"(b))

__global__ __launch_bounds__(256, 3) void kc_mfma(
    const u64* __restrict__ xbits,
    const int8_t* __restrict__ Bfrag,
    short* __restrict__ S,           // [NPOS][256]
    int* __restrict__ ssum,
    unsigned long long* __restrict__ qsum)
{
    const int blk = blockIdx.x;        // (b,h)
    const int b = blk / H_;
    const int h = blk - b * H_;
    const int tid = threadIdx.x;

    __shared__ u32 ldsb[3 * 58 * 64];  // 44544 B

    for (int it = tid; it < 3 * 58 * 16; it += 256) {
        const int r = it / 928;              // 58*16
        const int rem = it - r * 928;
        const int wp = rem >> 4;
        const int g = rem & 15;
        const int hr = h - 1 + r;
        const int w_in = wp - 1;
        const bool inb = (hr >= 0) && (hr < H_) && (w_in >= 0) && (w_in < W_);
        u32 chunk16 = 0;
        if (inb) {
            const u64 word = xbits[((size_t)(b * HW + hr * W_ + w_in)) * 4 + (g >> 2)];
            chunk16 = (u32)(word >> ((g & 3) * 16)) & 0xFFFFu;
        }
        u32 out4[4];
#pragma unroll
        for (int d = 0; d < 4; ++d) {
            const u32 nib = (chunk16 >> (4 * d)) & 0xFu;
            const u32 m1 = (nib * 0x00204081u) & 0x01010101u;   // bit u -> byte u
            const u32 inv = m1 ^ 0x01010101u;
            out4[d] = inb ? (0x01010101u ^ (inv * 0xFEu)) : 0u; // 1->+1, 0->-1, OOB->0
        }
        const int gs = (g + wp) & 15;
        u32* dst = &ldsb[((r * 58 + wp) << 6) + gs * 4];
        dst[0] = out4[0]; dst[1] = out4[1]; dst[2] = out4[2]; dst[3] = out4[3];
    }
    __syncthreads();

    const int m0 = tid & 31;           // M row within tile
    const int lh = (tid >> 5) & 1;     // k-half selector
    const int wv = tid >> 6;           // wave id: N cols 64*wv .. 64*wv+63
    const int8_t* smem = (const int8_t*)ldsb;
    const int8_t* Bp = Bfrag + (size_t)(tid & 63) * 16;

    auto ldA = [&](int kk, int mt) -> v4i {
        const int tap = kk >> 3, s = kk & 7;   // constant after unroll
        const int dh = tap / 3;
        const int dw = tap - dh * 3;
        const int wpm = min(mt * 32 + m0 + dw, 57);
        const int gs = (2 * s + lh + wpm) & 15;
        const int addr = ((dh * 58 + wpm) << 8) + (gs << 4);
        return *(const v4i*)(smem + addr);
    };
    auto ldB = [&](int kk, int ntl) -> v4i {
        const size_t off = (size_t)((kk * 8) + wv * 2 + ntl) * 1024;
        return *(const v4i*)(Bp + off);
    };

    v16i acc00 = {0}, acc01 = {0}, acc10 = {0}, acc11 = {0};
    v4i A0[2], A1[2], Bb0[2], Bb1[2];

    A0[0] = ldA(0, 0); A1[0] = ldA(0, 1);
    Bb0[0] = ldB(0, 0); Bb1[0] = ldB(0, 1);

#pragma unroll
    for (int kk = 0; kk < 72; ++kk) {
        const int cur = kk & 1, nxt = cur ^ 1;
        if (kk < 71) {
            A0[nxt] = ldA(kk + 1, 0); A1[nxt] = ldA(kk + 1, 1);
            Bb0[nxt] = ldB(kk + 1, 0); Bb1[nxt] = ldB(kk + 1, 1);
        }
        MFMA_I8(acc00, A0[cur], Bb0[cur]);
        MFMA_I8(acc01, A0[cur], Bb1[cur]);
        MFMA_I8(acc10, A1[cur], Bb0[cur]);
        MFMA_I8(acc11, A1[cur], Bb1[cur]);
    }

    // drain MFMA pipe before AGPR reads (compiler is blind to asm latency)
    asm volatile("s_nop 7\n\ts_nop 7\n\ts_nop 7"
                 : "+a"(acc00), "+a"(acc01), "+a"(acc10), "+a"(acc11));

    // C/D layout: n = nt*32 + (lane&31); m = mt*32 + (reg&3) + 8*(reg>>2) + 4*lh
    const int n0 = wv * 64 + m0;
    const int n1 = n0 + 32;
    const int rowbase = b * HW + h * W_;
    int s0 = 0, s1 = 0, q0 = 0, q1 = 0;

#pragma unroll
    for (int reg = 0; reg < 16; ++reg) {     // mt = 0: all rows valid (m<32)
        const int m = (reg & 3) + ((reg >> 2) << 3) + (lh << 2);
        const int v0 = acc00[reg], v1 = acc01[reg];
        s0 += v0; q0 += v0 * v0; s1 += v1; q1 += v1 * v1;
        S[(size_t)(rowbase + m) * 256 + n0] = (short)v0;
        S[(size_t)(rowbase + m) * 256 + n1] = (short)v1;
    }
#pragma unroll
    for (int reg = 0; reg < 12; ++reg) {     // mt = 1: rows 32..55 only (reg<12)
        const int m = 32 + (reg & 3) + ((reg >> 2) << 3) + (lh << 2);
        const int v0 = acc10[reg], v1 = acc11[reg];
        s0 += v0; q0 += v0 * v0; s1 += v1; q1 += v1 * v1;
        S[(size_t)(rowbase + m) * 256 + n0] = (short)v0;
        S[(size_t)(rowbase + m) * 256 + n1] = (short)v1;
    }

    s0 += __shfl_xor(s0, 32, 64); q0 += __shfl_xor(q0, 32, 64);
    s1 += __shfl_xor(s1, 32, 64); q1 += __shfl_xor(q1, 32, 64);
    if (lh == 0) {
        atomicAdd(&ssum[n0], s0);
        atomicAdd(&qsum[n0], (unsigned long long)(long long)q0);
        atomicAdd(&ssum[n1], s1);
        atomicAdd(&qsum[n1], (unsigned long long)(long long)q1);
    }
}

// ---------------- Kernel 3: BN finalize + NHWC->NCHW transpose + ReLU ----------------
// One block per (b, c64-group, 64-position chunk): max TLP, single pass.
__global__ __launch_bounds__(256) void kb_apply(
    const short* __restrict__ S,
    const int* __restrict__ ssum,
    const unsigned long long* __restrict__ qsum,
    const float* __restrict__ alpha,
    const float* __restrict__ gamma,
    const float* __restrict__ beta,
    float* __restrict__ out)
{
    const int blk = blockIdx.x;              // ((b*4 + cg)*49 + chunk)
    const int chunk = blk % 49;
    const int bcg = blk / 49;
    const int cg = bcg & 3;
    const int b = bcg >> 2;
    const int c0 = cg * 64;
    const int p0 = chunk * 64;
    const int tid = threadIdx.x;

    __shared__ float s_scale[64], s_shift[64];
    __shared__ u32 lds[64 * 33];             // [p][cpair], stride 33 dwords

    if (tid < 64) {                          // BN finalize for this c-group
        const int o = c0 + tid;
        const double N = (double)NPOS;
        double meanS = (double)ssum[o] / N;
        double varS = (double)qsum[o] / N - meanS * meanS;
        double a = (double)alpha[o];
        double rstd = 1.0 / sqrt(a * a * varS + 1e-5);
        double g = (double)gamma[o];
        s_scale[tid] = (float)(g * a * rstd);
        s_shift[tid] = (float)((double)beta[o] - g * a * meanS * rstd);
        // conv bias cancels exactly in training-mode BN
    }

    // read 64p x 64c: 2048 u32, 8 per thread, full-line coalesced
    const u32* Sp = (const u32*)(S + ((size_t)b * HW + p0) * 256 + c0);
#pragma unroll
    for (int k = 0; k < 8; ++k) {
        const int idx = tid + k * 256;       // 0..2047
        const int p = idx >> 5, cp = idx & 31;
        lds[p * 33 + cp] = Sp[p * 128 + cp];
    }
    __syncthreads();

    // write: lanes = consecutive p -> 256B contiguous stores
    const int pl = tid & 63;
    const int ch4 = tid >> 6;                // 4 groups of 16 channels
    const short* lss = (const short*)lds;
#pragma unroll
    for (int cc = 0; cc < 16; ++cc) {
        const int c = ch4 * 16 + cc;
        const float f = fmaxf(fmaf((float)lss[pl * 66 + c], s_scale[c], s_shift[c]), 0.0f);
        out[((size_t)(b * COUT + c0 + c)) * HW + p0 + pl] = f;
    }
}

extern "C" void kernel_launch(void* const* d_in, const int* in_sizes, int n_in,
                              void* d_out, int out_size, void* d_ws, size_t ws_size,
                              hipStream_t stream) {
    const float* x     = (const float*)d_in[0];   // [32,256,56,56]
    const float* wgt   = (const float*)d_in[1];   // [256,256,3,3]
    // d_in[2] = bias: cancels exactly in BN, unused
    const float* gamma = (const float*)d_in[3];
    const float* beta  = (const float*)d_in[4];
    float* out = (float*)d_out;

    char* ws = (char*)d_ws;
    int8_t* Bfrag = (int8_t*)(ws + 0);
    float* alpha = (float*)(ws + 589824);
    int*   ssum  = (int*)(ws + 590848);
    unsigned long long* qsum = (unsigned long long*)(ws + 591872);
    u64*   xbits = (u64*)(ws + 593920);
    short* Sarr  = (short*)(ws + 3805184);

    k_prep<<<NPACKBLK + 256, 256, 0, stream>>>(x, wgt, xbits, Bfrag, alpha, ssum, qsum);
    kc_mfma<<<NROW, 256, 0, stream>>>(xbits, Bfrag, Sarr, ssum, qsum);
    kb_apply<<<32 * 4 * 49, 256, 0, stream>>>(Sarr, ssum, qsum, alpha, gamma, beta, out);
}